// Round 6
// baseline (132.037 us; speedup 1.0000x reference)
//
#include <hip/hip_runtime.h>
#include <hip/hip_bf16.h>

#define NROWS 65536
#define DIM   256
#define KC    512
#define ALPHA 0.05f

#define BM   32    // rows per block
#define SLD  264   // LDS row stride in bf16 elems (528 B = 33*16: 16B-aligned)

typedef __attribute__((ext_vector_type(8))) short bf16x8;
typedef __attribute__((ext_vector_type(4))) float f32x4;

static __device__ __forceinline__ unsigned short f2bf(float f) {
    union { __hip_bfloat16 h; unsigned short u; } c;
    c.h = __float2bfloat16(f);
    return c.u;
}
static __device__ __forceinline__ float bf2f(unsigned short u) {
    union { unsigned short u; __hip_bfloat16 h; } c;
    c.u = u;
    return __bfloat162float(c.h);
}

// Fragment-major center layout (verified r0/r3/r5): col-group cg (16 centers),
// k-step kk, lane l = q*16+m holds center row cg*16+m, elems kk*32+q*8..+7.
// uint4 index = (cg*8+kk)*64 + l.
__global__ void prep_centers(const float* __restrict__ centers,
                             float* __restrict__ csqh,
                             uint4* __restrict__ cbf2,
                             float* __restrict__ out) {
    const int t = threadIdx.x;
    const int r = blockIdx.x * 8 + (t >> 5);  // center row
    const int e = t & 31;                     // 8-elem group within row
    const float4* cv = reinterpret_cast<const float4*>(centers);
    float4 v0 = cv[r * 64 + e * 2];
    float4 v1 = cv[r * 64 + e * 2 + 1];
    float s = v0.x * v0.x + v0.y * v0.y + v0.z * v0.z + v0.w * v0.w
            + v1.x * v1.x + v1.y * v1.y + v1.z * v1.z + v1.w * v1.w;
    unsigned short o[8];
    o[0] = f2bf(v0.x); o[1] = f2bf(v0.y); o[2] = f2bf(v0.z); o[3] = f2bf(v0.w);
    o[4] = f2bf(v1.x); o[5] = f2bf(v1.y); o[6] = f2bf(v1.z); o[7] = f2bf(v1.w);
    const int cg = r >> 4, m = r & 15;
    const int kk = e >> 2, q = e & 3, l = q * 16 + m;
    cbf2[(cg * 8 + kk) * 64 + l] = *reinterpret_cast<uint4*>(o);
    #pragma unroll
    for (int off = 16; off; off >>= 1) s += __shfl_xor(s, off, 64);
    if (e == 0) csqh[r] = 0.5f * s;
    if (blockIdx.x == 0 && t == 0) out[0] = 0.f;  // separate dispatch -> ordered
}

// 32-row blocks, 4 waves: wave w owns rows [blk*32,+32) x cols [w*128,+128).
// A staged once in 17KB LDS; A-fragments then PINNED in VGPRs via opaque asm
// (r5 post-mortem: at VGPR=76 the compiler rematerialized the ds_read_b128
// inside every cg iteration -> 4096 LDS reads/CU on the critical path).
// Budget: afr 64 + bcur 32 + acc 8 + maxv 8 + c2h 8 + addr ~20 ~= 140-160 < 170
// (the (256,3) cap) -> no spill, 12 waves/CU.
__global__ __launch_bounds__(256, 3) void kmeans_main(
    const float* __restrict__ emb,
    const uint4* __restrict__ cbf2,
    const float* __restrict__ csqh_g,
    float* __restrict__ out) {
    __shared__ unsigned short sA[BM * SLD];   // 16896 B
    __shared__ float lmax[4][BM];
    __shared__ float lx2[BM];

    const int t = threadIdx.x;
    const int w = t >> 6;
    const int lane = t & 63;
    const int m = lane & 15;
    const int q = lane >> 4;
    const int row0 = blockIdx.x * BM;

    // ---- stage A tile: fp32 global -> bf16 LDS (coalesced float4) ----
    const float4* embv = reinterpret_cast<const float4*>(emb + (size_t)row0 * DIM);
    #pragma unroll
    for (int i = 0; i < 8; ++i) {
        int f = t + 256 * i;
        int r = f >> 6;
        int c4 = f & 63;
        float4 v = embv[r * 64 + c4];
        ushort4 o;
        o.x = f2bf(v.x); o.y = f2bf(v.y); o.z = f2bf(v.z); o.w = f2bf(v.w);
        *reinterpret_cast<ushort4*>(&sA[r * SLD + c4 * 4]) = o;
    }
    __syncthreads();

    // ---- x_sq per row from staged bf16 (8 threads per row) ----
    {
        int r = t >> 3;
        int g = t & 7;
        const ushort4* p = reinterpret_cast<const ushort4*>(&sA[r * SLD + g * 32]);
        float s = 0.f;
        #pragma unroll
        for (int j = 0; j < 8; ++j) {
            ushort4 u = p[j];
            float a = bf2f(u.x), b = bf2f(u.y), c = bf2f(u.z), d = bf2f(u.w);
            s += a * a + b * b + c * c + d * d;
        }
        s += __shfl_xor(s, 1, 64);
        s += __shfl_xor(s, 2, 64);
        s += __shfl_xor(s, 4, 64);
        if (g == 0) lx2[r] = s;
    }

    // ---- A fragments: ONE ds_read_b128 each, then pinned in VGPRs.
    //      The empty volatile asm makes the value an opaque def the compiler
    //      cannot rematerialize from LDS inside the cg loop. ----
    bf16x8 afr[2][8];
    #pragma unroll
    for (int rt = 0; rt < 2; ++rt)
        #pragma unroll
        for (int k = 0; k < 8; ++k) {
            bf16x8 v = *reinterpret_cast<const bf16x8*>(
                &sA[(rt * 16 + m) * SLD + k * 32 + q * 8]);
            asm volatile("" : "+v"(v));
            afr[rt][k] = v;
        }

    // ---- preload -c^2/2 for this wave's 8 col-groups (col = g*16+m) ----
    float c2h[8];
    #pragma unroll
    for (int cg = 0; cg < 8; ++cg) c2h[cg] = csqh_g[(w * 8 + cg) * 16 + m];

    // ---- stream this wave's 8 col-groups (fully unrolled straight-line:
    //      scheduler pipelines B loads across iterations in the reg headroom) ----
    const bf16x8* cb2 = reinterpret_cast<const bf16x8*>(cbf2);
    float maxv[2][4];
    #pragma unroll
    for (int rt = 0; rt < 2; ++rt)
        #pragma unroll
        for (int rg = 0; rg < 4; ++rg) maxv[rt][rg] = -1e30f;

    #pragma unroll
    for (int cg = 0; cg < 8; ++cg) {
        const int g = w * 8 + cg;              // global 16-col group
        bf16x8 bcur[8];
        #pragma unroll
        for (int kk = 0; kk < 8; ++kk)
            bcur[kk] = cb2[(g * 8 + kk) * 64 + lane];
        const float ci = -c2h[cg];
        f32x4 acc[2];
        acc[0] = (f32x4){ci, ci, ci, ci};
        acc[1] = (f32x4){ci, ci, ci, ci};
        #pragma unroll
        for (int kk = 0; kk < 8; ++kk)
            #pragma unroll
            for (int rt = 0; rt < 2; ++rt)
                acc[rt] = __builtin_amdgcn_mfma_f32_16x16x32_bf16(
                    afr[rt][kk], bcur[kk], acc[rt], 0, 0, 0);
        #pragma unroll
        for (int rt = 0; rt < 2; ++rt)
            #pragma unroll
            for (int rg = 0; rg < 4; ++rg)
                maxv[rt][rg] = fmaxf(maxv[rt][rg], acc[rt][rg]);
    }

    // ---- per-wave max over its 16 cols (xor over lane&15); row = rt*16+q*4+rg ----
    #pragma unroll
    for (int rt = 0; rt < 2; ++rt)
        #pragma unroll
        for (int rg = 0; rg < 4; ++rg) {
            float v = maxv[rt][rg];
            v = fmaxf(v, __shfl_xor(v, 1, 64));
            v = fmaxf(v, __shfl_xor(v, 2, 64));
            v = fmaxf(v, __shfl_xor(v, 4, 64));
            v = fmaxf(v, __shfl_xor(v, 8, 64));
            if (m == 0) lmax[w][rt * 16 + q * 4 + rg] = v;
        }
    __syncthreads();

    // ---- combine 4 col-quarters, d = sqrt(x2 - 2*max), block sum ----
    if (t < 32) {
        float M = fmaxf(fmaxf(lmax[0][t], lmax[1][t]),
                        fmaxf(lmax[2][t], lmax[3][t]));
        float d = sqrtf(fmaxf(lx2[t] - 2.f * M, 0.f));
        #pragma unroll
        for (int off = 1; off < 32; off <<= 1) d += __shfl_xor(d, off, 64);
        if (t == 0) atomicAdd(out, d * (ALPHA / (float)NROWS));
    }
}

extern "C" void kernel_launch(void* const* d_in, const int* in_sizes, int n_in,
                              void* d_out, int out_size, void* d_ws, size_t ws_size,
                              hipStream_t stream) {
    const float* emb     = (const float*)d_in[0];   // [65536, 256] fp32
    const float* centers = (const float*)d_in[1];   // [512, 256] fp32
    float* out = (float*)d_out;

    float* csqh = (float*)d_ws;                       // 512 * 4 B
    uint4* cbf2 = (uint4*)((char*)d_ws + 2048);       // 256 KB fragment-major bf16

    prep_centers<<<dim3(KC / 8), dim3(256), 0, stream>>>(centers, csqh, cbf2, out);
    kmeans_main<<<dim3(NROWS / BM), dim3(256), 0, stream>>>(emb, cbf2, csqh, out);
}

// Round 8
// 114.846 us; speedup vs baseline: 1.1497x; 1.1497x over previous
//
#include <hip/hip_runtime.h>
#include <hip/hip_bf16.h>

#define NROWS 65536
#define DIM   256
#define KC    512
#define ALPHA 0.05f

#define TROWS 16     // rows per tile
#define NTILE 16     // tiles per block -> 256 rows per block, grid = 256 = 1/CU
#define SLD   264    // LDS row stride in bf16 (528 B; 2-way-free bank skew)

typedef __attribute__((ext_vector_type(8))) short bf16x8;
typedef __attribute__((ext_vector_type(4))) float f32x4;

static __device__ __forceinline__ unsigned short f2bf(float f) {
    union { __hip_bfloat16 h; unsigned short u; } c;
    c.h = __float2bfloat16(f);
    return c.u;
}
static __device__ __forceinline__ float bf2f(unsigned short u) {
    union { unsigned short u; __hip_bfloat16 h; } c;
    c.u = u;
    return __bfloat162float(c.h);
}

// Fragment-major center layout (verified r0/r3/r5): col-group cg (16 centers),
// k-step kk, lane l = q*16+m holds center row cg*16+m, elems kk*32+q*8..+7.
// uint4 index = (cg*8+kk)*64 + l.
__global__ void prep_centers(const float* __restrict__ centers,
                             float* __restrict__ csqh,
                             uint4* __restrict__ cbf2,
                             float* __restrict__ out) {
    const int t = threadIdx.x;
    const int r = blockIdx.x * 8 + (t >> 5);  // center row
    const int e = t & 31;                     // 8-elem group within row
    const float4* cv = reinterpret_cast<const float4*>(centers);
    float4 v0 = cv[r * 64 + e * 2];
    float4 v1 = cv[r * 64 + e * 2 + 1];
    float s = v0.x * v0.x + v0.y * v0.y + v0.z * v0.z + v0.w * v0.w
            + v1.x * v1.x + v1.y * v1.y + v1.z * v1.z + v1.w * v1.w;
    unsigned short o[8];
    o[0] = f2bf(v0.x); o[1] = f2bf(v0.y); o[2] = f2bf(v0.z); o[3] = f2bf(v0.w);
    o[4] = f2bf(v1.x); o[5] = f2bf(v1.y); o[6] = f2bf(v1.z); o[7] = f2bf(v1.w);
    const int cg = r >> 4, m = r & 15;
    const int kk = e >> 2, q = e & 3, l = q * 16 + m;
    cbf2[(cg * 8 + kk) * 64 + l] = *reinterpret_cast<uint4*>(o);
    #pragma unroll
    for (int off = 16; off; off >>= 1) s += __shfl_xor(s, off, 64);
    if (e == 0) csqh[r] = 0.5f * s;
    if (blockIdx.x == 0 && t == 0) out[0] = 0.f;  // separate dispatch -> ordered
}

// Stationary-B: 512-thread blocks; wave ww pins B for centers [ww*64, ww*64+64)
// in 128 VGPRs (4 cg x 8 kk frags). A streamed once: 16-row tiles, reg-staged
// fp32 -> bf16 LDS (double-buffered), 2-tile-deep prefetch, raw barriers (no
// vmcnt drain). Inner loop has ZERO global loads: 8 x (ds_read_b128 + 4 MFMA).
__global__ __launch_bounds__(512, 2) void kmeans_main(
    const float* __restrict__ emb,
    const uint4* __restrict__ cbf2,
    const float* __restrict__ csqh_g,
    float* __restrict__ out) {
    __shared__ unsigned short sA[2][TROWS * SLD];  // 2 x 8448 B
    __shared__ float lmax[8][16];
    __shared__ float lx2[2][16];

    const int t = threadIdx.x;      // 0..511
    const int ww = t >> 6;          // wave 0..7
    const int lane = t & 63;
    const int m = lane & 15;
    const int q = lane >> 4;
    const int rr = t >> 5;          // staging row 0..15 (32 threads per row)
    const int e  = t & 31;          // staging 4-elem group

    // ---- B stationary: 4 col-groups (64 centers) per wave, pinned ----
    const bf16x8* cb2 = reinterpret_cast<const bf16x8*>(cbf2);
    bf16x8 bfr[4][8];
    #pragma unroll
    for (int c = 0; c < 4; ++c)
        #pragma unroll
        for (int kk = 0; kk < 8; ++kk) {
            bf16x8 v = cb2[(((ww * 4 + c) * 8) + kk) * 64 + lane];
            asm volatile("" : "+v"(v));   // opaque def: no remat/demote
            bfr[c][kk] = v;
        }
    float c2h[4];
    #pragma unroll
    for (int c = 0; c < 4; ++c) c2h[c] = csqh_g[(ww * 4 + c) * 16 + m];

    const float4* embv = reinterpret_cast<const float4*>(emb)
                       + (size_t)blockIdx.x * 256 * 64;   // block's 256 rows

    // stage helper lambdas (no token pasting; T is compile-time in unrolled loop)
    auto A_LOAD = [&](int T, float4& l0, float4& l1) {
        l0 = embv[(T * 16 + rr) * 64 + e];
        l1 = embv[(T * 16 + rr) * 64 + 32 + e];
    };
    auto A_STAGE = [&](int T, float4 l0, float4 l1) {
        ushort4 o0, o1;
        o0.x = f2bf(l0.x); o0.y = f2bf(l0.y); o0.z = f2bf(l0.z); o0.w = f2bf(l0.w);
        o1.x = f2bf(l1.x); o1.y = f2bf(l1.y); o1.z = f2bf(l1.z); o1.w = f2bf(l1.w);
        *reinterpret_cast<ushort4*>(&sA[T & 1][rr * SLD + e * 4]) = o0;
        *reinterpret_cast<ushort4*>(&sA[T & 1][rr * SLD + 128 + e * 4]) = o1;
        float xa = bf2f(o0.x), xb = bf2f(o0.y), xc = bf2f(o0.z), xd = bf2f(o0.w);
        float xe = bf2f(o1.x), xf = bf2f(o1.y), xg = bf2f(o1.z), xh = bf2f(o1.w);
        float xs = xa*xa + xb*xb + xc*xc + xd*xd + xe*xe + xf*xf + xg*xg + xh*xh;
        xs += __shfl_xor(xs, 1, 64);  xs += __shfl_xor(xs, 2, 64);
        xs += __shfl_xor(xs, 4, 64);  xs += __shfl_xor(xs, 8, 64);
        xs += __shfl_xor(xs, 16, 64);
        if (e == 0) lx2[T & 1][rr] = xs;
    };

    float4 ldA0, ldA1, ldB0, ldB1;
    float dsum = 0.f;

    // ---- prologue: T0 -> setA, T1 -> setB; stage T0 into buf0 ----
    A_LOAD(0, ldA0, ldA1);
    A_LOAD(1, ldB0, ldB1);
    A_STAGE(0, ldA0, ldA1);

    #pragma unroll
    for (int tt = 0; tt < NTILE; ++tt) {
        // stage tile tt+1 into buf[(tt+1)&1] (set alternates B,A,B,...)
        if (tt + 1 < NTILE) {
            if ((tt & 1) == 0) A_STAGE(tt + 1, ldB0, ldB1);
            else               A_STAGE(tt + 1, ldA0, ldA1);
        }
        // issue loads for tile tt+2 into the set just freed
        if (tt + 2 < NTILE) {
            if ((tt & 1) == 0) A_LOAD(tt + 2, ldA0, ldA1);
            else               A_LOAD(tt + 2, ldB0, ldB1);
        }
        // BAR1: staging of buf[tt&1] (done at iter tt-1 / prologue) visible;
        // raw barrier -> in-flight global prefetch survives.
        asm volatile("s_waitcnt lgkmcnt(0)\n\ts_barrier" ::: "memory");

        // ---- compute tile tt: 8 x (ds_read_b128 A-frag + 4 MFMA) ----
        f32x4 acc[4];
        #pragma unroll
        for (int c = 0; c < 4; ++c) {
            const float ci = -c2h[c];
            acc[c] = (f32x4){ci, ci, ci, ci};
        }
        #pragma unroll
        for (int kk = 0; kk < 8; ++kk) {
            bf16x8 a = *reinterpret_cast<const bf16x8*>(
                &sA[tt & 1][m * SLD + kk * 32 + q * 8]);
            #pragma unroll
            for (int c = 0; c < 4; ++c)
                acc[c] = __builtin_amdgcn_mfma_f32_16x16x32_bf16(
                    a, bfr[c][kk], acc[c], 0, 0, 0);
        }
        // fold 4 col-groups, then max over m (16 centers per group)
        f32x4 mx;
        #pragma unroll
        for (int rg = 0; rg < 4; ++rg) {
            float v = fmaxf(fmaxf(acc[0][rg], acc[1][rg]),
                            fmaxf(acc[2][rg], acc[3][rg]));
            v = fmaxf(v, __shfl_xor(v, 1, 64));
            v = fmaxf(v, __shfl_xor(v, 2, 64));
            v = fmaxf(v, __shfl_xor(v, 4, 64));
            v = fmaxf(v, __shfl_xor(v, 8, 64));
            mx[rg] = v;
        }
        if (m == 0)
            *reinterpret_cast<float4*>(&lmax[ww][q * 4]) =
                (float4){mx[0], mx[1], mx[2], mx[3]};

        // BAR2: lmax/lx2 of tile tt visible; also fences buf[(tt+1)&1] reuse
        // (compute of tile tt-1 finished before iter tt's staging began).
        asm volatile("s_waitcnt lgkmcnt(0)\n\ts_barrier" ::: "memory");

        // ---- combine: row t gets max over 8 waves (512 centers) ----
        if (t < 16) {
            float M = lmax[0][t];
            #pragma unroll
            for (int j = 1; j < 8; ++j) M = fmaxf(M, lmax[j][t]);
            dsum += sqrtf(fmaxf(lx2[tt & 1][t] - 2.f * M, 0.f));
        }
    }

    // ---- block sum of the 16 row-accumulators, one atomic per block ----
    if (t < 16) {
        dsum += __shfl_xor(dsum, 1, 64);
        dsum += __shfl_xor(dsum, 2, 64);
        dsum += __shfl_xor(dsum, 4, 64);
        dsum += __shfl_xor(dsum, 8, 64);
        if (t == 0) atomicAdd(out, dsum * (ALPHA / (float)NROWS));
    }
}

extern "C" void kernel_launch(void* const* d_in, const int* in_sizes, int n_in,
                              void* d_out, int out_size, void* d_ws, size_t ws_size,
                              hipStream_t stream) {
    const float* emb     = (const float*)d_in[0];   // [65536, 256] fp32
    const float* centers = (const float*)d_in[1];   // [512, 256] fp32
    float* out = (float*)d_out;

    float* csqh = (float*)d_ws;                       // 512 * 4 B
    uint4* cbf2 = (uint4*)((char*)d_ws + 2048);       // 256 KB fragment-major bf16

    prep_centers<<<dim3(KC / 8), dim3(256), 0, stream>>>(centers, csqh, cbf2, out);
    kmeans_main<<<dim3(NROWS / 256), dim3(512), 0, stream>>>(emb, cbf2, csqh, out);
}